// Round 9
// baseline (130.071 us; speedup 1.0000x reference)
//
#include <hip/hip_runtime.h>

#define B_TOT 8192
#define PP 32
#define QQ 32
#define RR 8
#define H1 128
#define H2 64
#define PHH 16
#define PAIRS 1024
#define OUT_UNITS 8192

#define NBLK_MM 256    // main-role: 128 btiles x 2 which, 512 thr (8 waves)
#define NBLK_IA 2048   // interact-role: 32 b-tiles of 256 x 64 pp-groups

typedef float f32x16 __attribute__((ext_vector_type(16)));
typedef short s16x8  __attribute__((ext_vector_type(8)));

union FragU { s16x8 v; unsigned int u[4]; };

// pack hi16(lo),hi16(hi) -> one dword (bf16 truncation), element 2*d = lo
__device__ inline unsigned int pack_bf16(float lo, float hi) {
    return __builtin_amdgcn_perm(__float_as_uint(hi), __float_as_uint(lo), 0x07060302u);
}

// R7 lesson: min-waves=6 made the compiler spill MFMA accumulators
// (WRITE_SIZE 2->365 MB). Keep VGPR budget 128 (min-waves 4); body lands ~56.
// R8 lesson: 256-thr blocks left occupancy at 35% — staging/reduction grain.
// Now 512-thr blocks: LDS 35.3 KB -> 4 blocks/CU x 8 waves = 32 waves/CU.
union SharedU {
    union {
        struct {
            float zT[16][256];            // 16384 B
            float4 lwx[16][2];            // 512
            float4 lwz[16][2];            // 512
            float4 lhb[16][2];            // 512
            unsigned lpw1T[17][16][4];    // 4352 (entry p=16 = zeros)
            float lpb[16][16];            // 1024
            float lpw2[16][16];           // 1024
        } s;                              // 24320 B
        float red[256][33];               // 33792 B (aliases staging after K-loop)
    } ia;
    struct {
        float h1T[128][65];               // 33280 B
        float red2[8][64];                // 2048
    } mm;                                 // 35328 B
};

__global__ __launch_bounds__(512, 4) void fused_k(
    const float* __restrict__ x, const float* __restrict__ z,
    const float* __restrict__ xw1, const float* __restrict__ xb1,
    const float* __restrict__ xw2, const float* __restrict__ xb2,
    const float* __restrict__ xw3, const float* __restrict__ xb3,
    const float* __restrict__ zw1, const float* __restrict__ zb1,
    const float* __restrict__ zw2, const float* __restrict__ zb2,
    const float* __restrict__ zw3, const float* __restrict__ zb3,
    const float* __restrict__ xzw, const float* __restrict__ xzb,
    const float* __restrict__ pw1, const float* __restrict__ pb1,
    const float* __restrict__ pw2, float* __restrict__ out)
{
    __shared__ SharedU sh;
    const int bid  = blockIdx.x;
    const int t    = threadIdx.x;
    const int w    = t >> 6;
    const int lane = t & 63;

    if (bid >= NBLK_MM) {
        // ------------------------- interaction role -------------------------
        const int ib    = bid - NBLK_MM;
        const int bx    = ib & 31;        // 32 b-tiles of 256
        const int y     = ib >> 5;        // 64 pp-groups
        const int m     = lane & 31;      // batch row within tile / C-D column
        const int kh    = lane >> 5;      // A k-half / pair selector
        const int jj    = m & 15;         // j within column's pair
        const int cph   = m >> 4;         // column's pair selector
        const int b0    = bx * 256;
        const int i_x   = y >> 1;
        const int k0    = (y & 1) * 16;
        const int pair0 = y * 16;

        // stage zT: 256 batches x 16 z-features (transposed)
        {
            int row = t >> 1;
            int c8  = (t & 1) * 8;
            const float* src = z + (size_t)(b0 + row) * 32 + k0 + c8;
            float4 a4 = *reinterpret_cast<const float4*>(src);
            float4 b4 = *reinterpret_cast<const float4*>(src + 4);
            sh.ia.s.zT[c8+0][row] = a4.x; sh.ia.s.zT[c8+1][row] = a4.y;
            sh.ia.s.zT[c8+2][row] = a4.z; sh.ia.s.zT[c8+3][row] = a4.w;
            sh.ia.s.zT[c8+4][row] = b4.x; sh.ia.s.zT[c8+5][row] = b4.y;
            sh.ia.s.zT[c8+6][row] = b4.z; sh.ia.s.zT[c8+7][row] = b4.w;
        }
        // stage h-layer weights (coalesced)
        if (t < 128) {
            int p = t >> 3, c = t & 7;
            int gp = pair0 + p;
            reinterpret_cast<float*>(sh.ia.s.lwx)[t] = xzw[(size_t)i_x * OUT_UNITS + gp*8 + c];
            reinterpret_cast<float*>(sh.ia.s.lwz)[t] = xzw[(size_t)(32 + k0 + p) * OUT_UNITS + gp*8 + c];
            reinterpret_cast<float*>(sh.ia.s.lhb)[t] = xzb[gp*8 + c];
        }
        // stage pb1 / pw2
        if (t < 256) {
            int p = t >> 4, j = t & 15;
            int gp = pair0 + p;
            sh.ia.s.lpb[p][j]  = pb1[gp*PHH + j];
            sh.ia.s.lpw2[p][j] = pw2[gp*PHH + j];
        }
        // stage pw1 pre-packed bf16, transposed to [p][j][u] for ds_read_b128
        #pragma unroll
        for (int it = 0; it < 2; ++it) {
            int idx = t + it * 512;           // 1024 dwords
            int p = idx >> 6, u = (idx >> 4) & 3, j = idx & 15;
            int gp = pair0 + p;
            float lo = pw1[(size_t)gp * 128 + (2*u)*16 + j];
            float hi = pw1[(size_t)gp * 128 + (2*u+1)*16 + j];
            sh.ia.s.lpw1T[p][j][u] = pack_bf16(lo, hi);
        }
        if (t < 64) reinterpret_cast<unsigned*>(sh.ia.s.lpw1T[16])[t] = 0u;

        const int g   = w >> 1;               // batch group (0..3)
        const int pph = w & 1;                // pp-half
        const int bl  = g * 64 + m;
        const float xv0 = x[(size_t)(b0 + bl)      * 32 + i_x];
        const float xv1 = x[(size_t)(b0 + bl + 32) * 32 + i_x];
        __syncthreads();

        f32x16 acc0, acc1;
        #pragma unroll
        for (int r = 0; r < 16; ++r) { acc0[r] = 0.f; acc1[r] = 0.f; }

        const bool realB = (kh == cph);

        #pragma unroll 2
        for (int kk = 0; kk < 4; ++kk) {
            const int ppl = pph * 4 + kk;
            const int pAl = 2*ppl + kh;
            const int pBl = 2*ppl + cph;

            const float zv0 = sh.ia.s.zT[pAl][bl];
            const float zv1 = sh.ia.s.zT[pAl][bl + 32];
            const float4 wxa = sh.ia.s.lwx[pAl][0], wxb = sh.ia.s.lwx[pAl][1];
            const float4 wza = sh.ia.s.lwz[pAl][0], wzb = sh.ia.s.lwz[pAl][1];
            const float4 hba = sh.ia.s.lhb[pAl][0], hbb = sh.ia.s.lhb[pAl][1];

            float h0[8], h1v[8];
            h0[0] = fmaxf(fmaf(xv0, wxa.x, fmaf(zv0, wza.x, hba.x)), 0.f);
            h0[1] = fmaxf(fmaf(xv0, wxa.y, fmaf(zv0, wza.y, hba.y)), 0.f);
            h0[2] = fmaxf(fmaf(xv0, wxa.z, fmaf(zv0, wza.z, hba.z)), 0.f);
            h0[3] = fmaxf(fmaf(xv0, wxa.w, fmaf(zv0, wza.w, hba.w)), 0.f);
            h0[4] = fmaxf(fmaf(xv0, wxb.x, fmaf(zv0, wzb.x, hbb.x)), 0.f);
            h0[5] = fmaxf(fmaf(xv0, wxb.y, fmaf(zv0, wzb.y, hbb.y)), 0.f);
            h0[6] = fmaxf(fmaf(xv0, wxb.z, fmaf(zv0, wzb.z, hbb.z)), 0.f);
            h0[7] = fmaxf(fmaf(xv0, wxb.w, fmaf(zv0, wzb.w, hbb.w)), 0.f);
            h1v[0] = fmaxf(fmaf(xv1, wxa.x, fmaf(zv1, wza.x, hba.x)), 0.f);
            h1v[1] = fmaxf(fmaf(xv1, wxa.y, fmaf(zv1, wza.y, hba.y)), 0.f);
            h1v[2] = fmaxf(fmaf(xv1, wxa.z, fmaf(zv1, wza.z, hba.z)), 0.f);
            h1v[3] = fmaxf(fmaf(xv1, wxa.w, fmaf(zv1, wza.w, hba.w)), 0.f);
            h1v[4] = fmaxf(fmaf(xv1, wxb.x, fmaf(zv1, wzb.x, hbb.x)), 0.f);
            h1v[5] = fmaxf(fmaf(xv1, wxb.y, fmaf(zv1, wzb.y, hbb.y)), 0.f);
            h1v[6] = fmaxf(fmaf(xv1, wxb.z, fmaf(zv1, wzb.z, hbb.z)), 0.f);
            h1v[7] = fmaxf(fmaf(xv1, wxb.w, fmaf(zv1, wzb.w, hbb.w)), 0.f);

            FragU a0, a1, bf;
            a0.u[0] = pack_bf16(h0[0], h0[1]);
            a0.u[1] = pack_bf16(h0[2], h0[3]);
            a0.u[2] = pack_bf16(h0[4], h0[5]);
            a0.u[3] = pack_bf16(h0[6], h0[7]);
            a1.u[0] = pack_bf16(h1v[0], h1v[1]);
            a1.u[1] = pack_bf16(h1v[2], h1v[3]);
            a1.u[2] = pack_bf16(h1v[4], h1v[5]);
            a1.u[3] = pack_bf16(h1v[6], h1v[7]);

            // B-frag: one index cndmask + ds_read_b128 (zeros at p=16)
            const unsigned* bq = sh.ia.s.lpw1T[realB ? pBl : 16][jj];
            bf.u[0] = bq[0]; bf.u[1] = bq[1]; bf.u[2] = bq[2]; bf.u[3] = bq[3];

            const float pbv = sh.ia.s.lpb[pBl][jj];
            const float w2v = sh.ia.s.lpw2[pBl][jj];

            f32x16 cpb;
            #pragma unroll
            for (int r = 0; r < 16; ++r) cpb[r] = pbv;

            f32x16 d0 = __builtin_amdgcn_mfma_f32_32x32x16_bf16(a0.v, bf.v, cpb, 0, 0, 0);
            f32x16 d1 = __builtin_amdgcn_mfma_f32_32x32x16_bf16(a1.v, bf.v, cpb, 0, 0, 0);

            #pragma unroll
            for (int r = 0; r < 16; ++r)
                acc0[r] = fmaf(fmaxf(d0[r], 0.f), w2v, acc0[r]);
            #pragma unroll
            for (int r = 0; r < 16; ++r)
                acc1[r] = fmaf(fmaxf(d1[r], 0.f), w2v, acc1[r]);
        }

        __syncthreads();   // staging LDS dead; red aliases it from here on
        const int rbase = g * 64;
        if (pph == 0) {
            #pragma unroll
            for (int r = 0; r < 16; ++r) {
                int rowf = (r & 3) + 8 * (r >> 2) + 4 * kh;
                sh.ia.red[rbase + rowf][m]      = acc0[r];
                sh.ia.red[rbase + 32 + rowf][m] = acc1[r];
            }
        }
        __syncthreads();
        if (pph == 1) {
            #pragma unroll
            for (int r = 0; r < 16; ++r) {
                int rowf = (r & 3) + 8 * (r >> 2) + 4 * kh;
                sh.ia.red[rbase + rowf][m]      += acc0[r];
                sh.ia.red[rbase + 32 + rowf][m] += acc1[r];
            }
        }
        __syncthreads();
        if (t < 256) {
            float s = 0.f;
            #pragma unroll
            for (int c = 0; c < 32; ++c) s += sh.ia.red[t][c];
            atomicAdd(out + b0 + t, s);
        }
    } else {
        // --------------------------- main-MLP role ---------------------------
        const int btile = bid & 127;
        const int which = bid >> 7;
        const float* in = which ? z   : x;
        const float* w1 = which ? zw1 : xw1;
        const float* b1 = which ? zb1 : xb1;
        const float* w2 = which ? zw2 : xw2;
        const float* b2 = which ? zb2 : xb2;
        const float* w3 = which ? zw3 : xw3;
        const float* b3 = which ? zb3 : xb3;

        const int wu = __builtin_amdgcn_readfirstlane(w);   // 0..7
        const int b0 = btile * 64;

        // input row in registers (each wave loads its lane's batch row)
        float xr[32];
        const float4* xrp = reinterpret_cast<const float4*>(in + (size_t)(b0 + lane) * 32);
        #pragma unroll
        for (int q = 0; q < 8; ++q) {
            float4 v = xrp[q];
            xr[4*q] = v.x; xr[4*q+1] = v.y; xr[4*q+2] = v.z; xr[4*q+3] = v.w;
        }

        // phase A: wave computes h1 j-slice [16wu, 16wu+16) for 64 batches
        const int j0 = wu * 16;
        float h1[16];
        #pragma unroll
        for (int j = 0; j < 16; ++j) h1[j] = b1[j0 + j];
        #pragma unroll
        for (int mm = 0; mm < 32; ++mm) {
            float xv = xr[mm];
            #pragma unroll
            for (int j = 0; j < 16; ++j)
                h1[j] = fmaf(xv, w1[mm*H1 + j0 + j], h1[j]);
        }
        #pragma unroll
        for (int j = 0; j < 16; ++j)
            sh.mm.h1T[j0 + j][lane] = fmaxf(h1[j], 0.f);
        __syncthreads();

        // phase B: wave computes h2 n-slice [8wu, 8wu+8)
        const int n0 = __builtin_amdgcn_readfirstlane(wu * 8);
        float h2[8];
        #pragma unroll
        for (int n = 0; n < 8; ++n) h2[n] = b2[n0 + n];
        #pragma unroll 4
        for (int mm = 0; mm < 128; ++mm) {
            float hv = sh.mm.h1T[mm][lane];
            #pragma unroll
            for (int n = 0; n < 8; ++n)
                h2[n] = fmaf(hv, w2[mm*H2 + n0 + n], h2[n]);
        }
        float p = 0.f;
        #pragma unroll
        for (int n = 0; n < 8; ++n)
            p = fmaf(fmaxf(h2[n], 0.f), w3[n0 + n], p);

        sh.mm.red2[wu][lane] = p;
        __syncthreads();
        if (t < 64) {
            float s = b3[0];
            #pragma unroll
            for (int ww = 0; ww < 8; ++ww) s += sh.mm.red2[ww][t];
            atomicAdd(out + b0 + t, s);
        }
    }
}

extern "C" void kernel_launch(void* const* d_in, const int* in_sizes, int n_in,
                              void* d_out, int out_size, void* d_ws, size_t ws_size,
                              hipStream_t stream) {
    const float* x   = (const float*)d_in[0];
    const float* z   = (const float*)d_in[1];
    const float* xw1 = (const float*)d_in[2];
    const float* xb1 = (const float*)d_in[3];
    const float* xw2 = (const float*)d_in[4];
    const float* xb2 = (const float*)d_in[5];
    const float* xw3 = (const float*)d_in[6];
    const float* xb3 = (const float*)d_in[7];
    const float* zw1 = (const float*)d_in[8];
    const float* zb1 = (const float*)d_in[9];
    const float* zw2 = (const float*)d_in[10];
    const float* zb2 = (const float*)d_in[11];
    const float* zw3 = (const float*)d_in[12];
    const float* zb3 = (const float*)d_in[13];
    const float* xzw = (const float*)d_in[14];
    const float* xzb = (const float*)d_in[15];
    const float* pw1 = (const float*)d_in[16];
    const float* pb1 = (const float*)d_in[17];
    const float* pw2 = (const float*)d_in[18];
    float* out = (float*)d_out;

    hipMemsetAsync(out, 0, (size_t)out_size * sizeof(float), stream);

    fused_k<<<dim3(NBLK_MM + NBLK_IA), 512, 0, stream>>>(
        x, z, xw1, xb1, xw2, xb2, xw3, xb3,
        zw1, zb1, zw2, zb2, zw3, zb3,
        xzw, xzb, pw1, pb1, pw2, out);
}

// Round 10
// 124.249 us; speedup vs baseline: 1.0469x; 1.0469x over previous
//
#include <hip/hip_runtime.h>

#define B_TOT 8192
#define PP 32
#define QQ 32
#define RR 8
#define H1 128
#define H2 64
#define PHH 16
#define PAIRS 1024
#define OUT_UNITS 8192

#define NBLK_MM 256    // main-role: 128 btiles x 2 which, 512 thr (8 waves)
#define NBLK_IA 2048   // interact-role: 32 b-tiles of 256 x 64 pp-groups

typedef float f32x16 __attribute__((ext_vector_type(16)));
typedef short s16x8  __attribute__((ext_vector_type(8)));

union FragU { s16x8 v; unsigned int u[4]; };

// pack hi16(lo),hi16(hi) -> one dword (bf16 truncation), element 2*d = lo
__device__ inline unsigned int pack_bf16(float lo, float hi) {
    return __builtin_amdgcn_perm(__float_as_uint(hi), __float_as_uint(lo), 0x07060302u);
}

// R7 lesson: min-waves=6 -> accumulator spill (WRITE_SIZE 2->365 MB). Keep 4.
// R9 lesson: ia-side regraining was neutral because the MAIN-MLP role was the
// floor: its weights were read at wave-uniform addresses -> s_load chains,
// ~30-40 us latency-dead per block (R5: standalone main at 40-58 us, VALUBusy
// 8.9%). This round mm is rewritten lane-per-neuron so EVERY weight load is a
// per-lane coalesced vector load (pipelined), LDS only for x/h1 broadcasts.
union SharedU {
    union {
        struct {
            float zT[16][256];            // 16384 B
            float4 lwx[16][2];            // 512
            float4 lwz[16][2];            // 512
            float4 lhb[16][2];            // 512
            unsigned lpw1T[17][16][4];    // 4352 (entry p=16 = zeros)
            float lpb[16][16];            // 1024
            float lpw2[16][16];           // 1024
        } s;                              // 24320 B
        float red[256][33];               // 33792 B (aliases staging after K-loop)
    } ia;
    struct {
        union {
            float xT[32][68];             // phase-A input (aliases h1T rows 0..31)
            float h1T[128][68];           // 34816 B; also reused as red[64][68]
        };
    } mm;
};

__global__ __launch_bounds__(512, 4) void fused_k(
    const float* __restrict__ x, const float* __restrict__ z,
    const float* __restrict__ xw1, const float* __restrict__ xb1,
    const float* __restrict__ xw2, const float* __restrict__ xb2,
    const float* __restrict__ xw3, const float* __restrict__ xb3,
    const float* __restrict__ zw1, const float* __restrict__ zb1,
    const float* __restrict__ zw2, const float* __restrict__ zb2,
    const float* __restrict__ zw3, const float* __restrict__ zb3,
    const float* __restrict__ xzw, const float* __restrict__ xzb,
    const float* __restrict__ pw1, const float* __restrict__ pb1,
    const float* __restrict__ pw2, float* __restrict__ out)
{
    __shared__ SharedU sh;
    const int bid  = blockIdx.x;
    const int t    = threadIdx.x;
    const int w    = t >> 6;
    const int lane = t & 63;

    if (bid >= NBLK_MM) {
        // ------------------------- interaction role (unchanged from R9) -----
        const int ib    = bid - NBLK_MM;
        const int bx    = ib & 31;        // 32 b-tiles of 256
        const int y     = ib >> 5;        // 64 pp-groups
        const int m     = lane & 31;      // batch row within tile / C-D column
        const int kh    = lane >> 5;      // A k-half / pair selector
        const int jj    = m & 15;         // j within column's pair
        const int cph   = m >> 4;         // column's pair selector
        const int b0    = bx * 256;
        const int i_x   = y >> 1;
        const int k0    = (y & 1) * 16;
        const int pair0 = y * 16;

        // stage zT: 256 batches x 16 z-features (transposed)
        {
            int row = t >> 1;
            int c8  = (t & 1) * 8;
            const float* src = z + (size_t)(b0 + row) * 32 + k0 + c8;
            float4 a4 = *reinterpret_cast<const float4*>(src);
            float4 b4 = *reinterpret_cast<const float4*>(src + 4);
            sh.ia.s.zT[c8+0][row] = a4.x; sh.ia.s.zT[c8+1][row] = a4.y;
            sh.ia.s.zT[c8+2][row] = a4.z; sh.ia.s.zT[c8+3][row] = a4.w;
            sh.ia.s.zT[c8+4][row] = b4.x; sh.ia.s.zT[c8+5][row] = b4.y;
            sh.ia.s.zT[c8+6][row] = b4.z; sh.ia.s.zT[c8+7][row] = b4.w;
        }
        // stage h-layer weights (coalesced)
        if (t < 128) {
            int p = t >> 3, c = t & 7;
            int gp = pair0 + p;
            reinterpret_cast<float*>(sh.ia.s.lwx)[t] = xzw[(size_t)i_x * OUT_UNITS + gp*8 + c];
            reinterpret_cast<float*>(sh.ia.s.lwz)[t] = xzw[(size_t)(32 + k0 + p) * OUT_UNITS + gp*8 + c];
            reinterpret_cast<float*>(sh.ia.s.lhb)[t] = xzb[gp*8 + c];
        }
        // stage pb1 / pw2
        if (t < 256) {
            int p = t >> 4, j = t & 15;
            int gp = pair0 + p;
            sh.ia.s.lpb[p][j]  = pb1[gp*PHH + j];
            sh.ia.s.lpw2[p][j] = pw2[gp*PHH + j];
        }
        // stage pw1 pre-packed bf16, transposed to [p][j][u] for ds_read_b128
        #pragma unroll
        for (int it = 0; it < 2; ++it) {
            int idx = t + it * 512;           // 1024 dwords
            int p = idx >> 6, u = (idx >> 4) & 3, j = idx & 15;
            int gp = pair0 + p;
            float lo = pw1[(size_t)gp * 128 + (2*u)*16 + j];
            float hi = pw1[(size_t)gp * 128 + (2*u+1)*16 + j];
            sh.ia.s.lpw1T[p][j][u] = pack_bf16(lo, hi);
        }
        if (t < 64) reinterpret_cast<unsigned*>(sh.ia.s.lpw1T[16])[t] = 0u;

        const int g   = w >> 1;               // batch group (0..3)
        const int pph = w & 1;                // pp-half
        const int bl  = g * 64 + m;
        const float xv0 = x[(size_t)(b0 + bl)      * 32 + i_x];
        const float xv1 = x[(size_t)(b0 + bl + 32) * 32 + i_x];
        __syncthreads();

        f32x16 acc0, acc1;
        #pragma unroll
        for (int r = 0; r < 16; ++r) { acc0[r] = 0.f; acc1[r] = 0.f; }

        const bool realB = (kh == cph);

        #pragma unroll 2
        for (int kk = 0; kk < 4; ++kk) {
            const int ppl = pph * 4 + kk;
            const int pAl = 2*ppl + kh;
            const int pBl = 2*ppl + cph;

            const float zv0 = sh.ia.s.zT[pAl][bl];
            const float zv1 = sh.ia.s.zT[pAl][bl + 32];
            const float4 wxa = sh.ia.s.lwx[pAl][0], wxb = sh.ia.s.lwx[pAl][1];
            const float4 wza = sh.ia.s.lwz[pAl][0], wzb = sh.ia.s.lwz[pAl][1];
            const float4 hba = sh.ia.s.lhb[pAl][0], hbb = sh.ia.s.lhb[pAl][1];

            float h0[8], h1v[8];
            h0[0] = fmaxf(fmaf(xv0, wxa.x, fmaf(zv0, wza.x, hba.x)), 0.f);
            h0[1] = fmaxf(fmaf(xv0, wxa.y, fmaf(zv0, wza.y, hba.y)), 0.f);
            h0[2] = fmaxf(fmaf(xv0, wxa.z, fmaf(zv0, wza.z, hba.z)), 0.f);
            h0[3] = fmaxf(fmaf(xv0, wxa.w, fmaf(zv0, wza.w, hba.w)), 0.f);
            h0[4] = fmaxf(fmaf(xv0, wxb.x, fmaf(zv0, wzb.x, hbb.x)), 0.f);
            h0[5] = fmaxf(fmaf(xv0, wxb.y, fmaf(zv0, wzb.y, hbb.y)), 0.f);
            h0[6] = fmaxf(fmaf(xv0, wxb.z, fmaf(zv0, wzb.z, hbb.z)), 0.f);
            h0[7] = fmaxf(fmaf(xv0, wxb.w, fmaf(zv0, wzb.w, hbb.w)), 0.f);
            h1v[0] = fmaxf(fmaf(xv1, wxa.x, fmaf(zv1, wza.x, hba.x)), 0.f);
            h1v[1] = fmaxf(fmaf(xv1, wxa.y, fmaf(zv1, wza.y, hba.y)), 0.f);
            h1v[2] = fmaxf(fmaf(xv1, wxa.z, fmaf(zv1, wza.z, hba.z)), 0.f);
            h1v[3] = fmaxf(fmaf(xv1, wxa.w, fmaf(zv1, wza.w, hba.w)), 0.f);
            h1v[4] = fmaxf(fmaf(xv1, wxb.x, fmaf(zv1, wzb.x, hbb.x)), 0.f);
            h1v[5] = fmaxf(fmaf(xv1, wxb.y, fmaf(zv1, wzb.y, hbb.y)), 0.f);
            h1v[6] = fmaxf(fmaf(xv1, wxb.z, fmaf(zv1, wzb.z, hbb.z)), 0.f);
            h1v[7] = fmaxf(fmaf(xv1, wxb.w, fmaf(zv1, wzb.w, hbb.w)), 0.f);

            FragU a0, a1, bf;
            a0.u[0] = pack_bf16(h0[0], h0[1]);
            a0.u[1] = pack_bf16(h0[2], h0[3]);
            a0.u[2] = pack_bf16(h0[4], h0[5]);
            a0.u[3] = pack_bf16(h0[6], h0[7]);
            a1.u[0] = pack_bf16(h1v[0], h1v[1]);
            a1.u[1] = pack_bf16(h1v[2], h1v[3]);
            a1.u[2] = pack_bf16(h1v[4], h1v[5]);
            a1.u[3] = pack_bf16(h1v[6], h1v[7]);

            // B-frag: one index cndmask + ds_read_b128 (zeros at p=16)
            const unsigned* bq = sh.ia.s.lpw1T[realB ? pBl : 16][jj];
            bf.u[0] = bq[0]; bf.u[1] = bq[1]; bf.u[2] = bq[2]; bf.u[3] = bq[3];

            const float pbv = sh.ia.s.lpb[pBl][jj];
            const float w2v = sh.ia.s.lpw2[pBl][jj];

            f32x16 cpb;
            #pragma unroll
            for (int r = 0; r < 16; ++r) cpb[r] = pbv;

            f32x16 d0 = __builtin_amdgcn_mfma_f32_32x32x16_bf16(a0.v, bf.v, cpb, 0, 0, 0);
            f32x16 d1 = __builtin_amdgcn_mfma_f32_32x32x16_bf16(a1.v, bf.v, cpb, 0, 0, 0);

            #pragma unroll
            for (int r = 0; r < 16; ++r)
                acc0[r] = fmaf(fmaxf(d0[r], 0.f), w2v, acc0[r]);
            #pragma unroll
            for (int r = 0; r < 16; ++r)
                acc1[r] = fmaf(fmaxf(d1[r], 0.f), w2v, acc1[r]);
        }

        __syncthreads();   // staging LDS dead; red aliases it from here on
        const int rbase = g * 64;
        if (pph == 0) {
            #pragma unroll
            for (int r = 0; r < 16; ++r) {
                int rowf = (r & 3) + 8 * (r >> 2) + 4 * kh;
                sh.ia.red[rbase + rowf][m]      = acc0[r];
                sh.ia.red[rbase + 32 + rowf][m] = acc1[r];
            }
        }
        __syncthreads();
        if (pph == 1) {
            #pragma unroll
            for (int r = 0; r < 16; ++r) {
                int rowf = (r & 3) + 8 * (r >> 2) + 4 * kh;
                sh.ia.red[rbase + rowf][m]      += acc0[r];
                sh.ia.red[rbase + 32 + rowf][m] += acc1[r];
            }
        }
        __syncthreads();
        if (t < 256) {
            float s = 0.f;
            #pragma unroll
            for (int c = 0; c < 32; ++c) s += sh.ia.red[t][c];
            atomicAdd(out + b0 + t, s);
        }
    } else {
        // --------------------------- main-MLP role ---------------------------
        // lane = neuron, wave = 8 batches; all weight loads per-lane coalesced.
        const int btile = bid & 127;
        const int which = bid >> 7;
        const float* in = which ? z   : x;
        const float* w1 = which ? zw1 : xw1;
        const float* b1 = which ? zb1 : xb1;
        const float* w2 = which ? zw2 : xw2;
        const float* b2 = which ? zb2 : xb2;
        const float* w3 = which ? zw3 : xw3;
        const float* b3 = which ? zb3 : xb3;
        const int b0 = btile * 64;
        const int bw = w * 8;            // this wave's local batch base

        // stage xT[32][68] transposed (aliases h1T rows 0..31)
        {
            int row = t >> 3;            // batch 0..63
            int c4  = (t & 7) * 4;       // feature 0..28 step 4
            float4 v = *reinterpret_cast<const float4*>(in + (size_t)(b0 + row) * 32 + c4);
            sh.mm.xT[c4+0][row] = v.x; sh.mm.xT[c4+1][row] = v.y;
            sh.mm.xT[c4+2][row] = v.z; sh.mm.xT[c4+3][row] = v.w;
        }
        __syncthreads();

        // phase A: h1 for neurons j=lane and lane+64, batches [bw, bw+8)
        const int j1 = lane, j2 = lane + 64;
        float a1[8], a2[8];
        {
            float bb1 = b1[j1], bb2 = b1[j2];
            #pragma unroll
            for (int i = 0; i < 8; ++i) { a1[i] = bb1; a2[i] = bb2; }
        }
        #pragma unroll 4
        for (int m = 0; m < 32; ++m) {
            const float4* xr = reinterpret_cast<const float4*>(&sh.mm.xT[m][bw]);
            float4 xa = xr[0], xb = xr[1];
            float wv1 = w1[m*H1 + j1];
            float wv2 = w1[m*H1 + j2];
            a1[0] = fmaf(xa.x, wv1, a1[0]); a2[0] = fmaf(xa.x, wv2, a2[0]);
            a1[1] = fmaf(xa.y, wv1, a1[1]); a2[1] = fmaf(xa.y, wv2, a2[1]);
            a1[2] = fmaf(xa.z, wv1, a1[2]); a2[2] = fmaf(xa.z, wv2, a2[2]);
            a1[3] = fmaf(xa.w, wv1, a1[3]); a2[3] = fmaf(xa.w, wv2, a2[3]);
            a1[4] = fmaf(xb.x, wv1, a1[4]); a2[4] = fmaf(xb.x, wv2, a2[4]);
            a1[5] = fmaf(xb.y, wv1, a1[5]); a2[5] = fmaf(xb.y, wv2, a2[5]);
            a1[6] = fmaf(xb.z, wv1, a1[6]); a2[6] = fmaf(xb.z, wv2, a2[6]);
            a1[7] = fmaf(xb.w, wv1, a1[7]); a2[7] = fmaf(xb.w, wv2, a2[7]);
        }
        __syncthreads();          // all xT reads done (h1T writes alias xT)
        #pragma unroll
        for (int i = 0; i < 8; ++i) {
            sh.mm.h1T[j1][bw + i] = fmaxf(a1[i], 0.f);
            sh.mm.h1T[j2][bw + i] = fmaxf(a2[i], 0.f);
        }
        __syncthreads();

        // phase B: h2 for neuron n=lane, batches [bw, bw+8)
        float hacc[8];
        {
            float b2v = b2[lane];
            #pragma unroll
            for (int i = 0; i < 8; ++i) hacc[i] = b2v;
        }
        #pragma unroll 4
        for (int m = 0; m < 128; ++m) {
            float w2v = w2[m*H2 + lane];
            const float4* hr = reinterpret_cast<const float4*>(&sh.mm.h1T[m][bw]);
            float4 ha = hr[0], hb = hr[1];
            hacc[0] = fmaf(ha.x, w2v, hacc[0]);
            hacc[1] = fmaf(ha.y, w2v, hacc[1]);
            hacc[2] = fmaf(ha.z, w2v, hacc[2]);
            hacc[3] = fmaf(ha.w, w2v, hacc[3]);
            hacc[4] = fmaf(hb.x, w2v, hacc[4]);
            hacc[5] = fmaf(hb.y, w2v, hacc[5]);
            hacc[6] = fmaf(hb.z, w2v, hacc[6]);
            hacc[7] = fmaf(hb.w, w2v, hacc[7]);
        }
        {
            float w3v = w3[lane];
            #pragma unroll
            for (int i = 0; i < 8; ++i) hacc[i] = fmaxf(hacc[i], 0.f) * w3v;
        }
        __syncthreads();          // phase-B h1T reads done (red aliases h1T)
        #pragma unroll
        for (int i = 0; i < 8; ++i)
            sh.mm.h1T[bw + i][lane] = hacc[i];   // red[b][n]
        __syncthreads();
        if (t < 64) {
            float s = b3[0];
            const float4* rr = reinterpret_cast<const float4*>(&sh.mm.h1T[t][0]);
            #pragma unroll
            for (int c = 0; c < 16; ++c) {
                float4 v = rr[c];
                s += (v.x + v.y) + (v.z + v.w);
            }
            atomicAdd(out + b0 + t, s);
        }
    }
}

extern "C" void kernel_launch(void* const* d_in, const int* in_sizes, int n_in,
                              void* d_out, int out_size, void* d_ws, size_t ws_size,
                              hipStream_t stream) {
    const float* x   = (const float*)d_in[0];
    const float* z   = (const float*)d_in[1];
    const float* xw1 = (const float*)d_in[2];
    const float* xb1 = (const float*)d_in[3];
    const float* xw2 = (const float*)d_in[4];
    const float* xb2 = (const float*)d_in[5];
    const float* xw3 = (const float*)d_in[6];
    const float* xb3 = (const float*)d_in[7];
    const float* zw1 = (const float*)d_in[8];
    const float* zb1 = (const float*)d_in[9];
    const float* zw2 = (const float*)d_in[10];
    const float* zb2 = (const float*)d_in[11];
    const float* zw3 = (const float*)d_in[12];
    const float* zb3 = (const float*)d_in[13];
    const float* xzw = (const float*)d_in[14];
    const float* xzb = (const float*)d_in[15];
    const float* pw1 = (const float*)d_in[16];
    const float* pb1 = (const float*)d_in[17];
    const float* pw2 = (const float*)d_in[18];
    float* out = (float*)d_out;

    hipMemsetAsync(out, 0, (size_t)out_size * sizeof(float), stream);

    fused_k<<<dim3(NBLK_MM + NBLK_IA), 512, 0, stream>>>(
        x, z, xw1, xb1, xw2, xb2, xw3, xb3,
        zw1, zb1, zw2, zb2, zw3, zb3,
        xzw, xzb, pw1, pb1, pw2, out);
}